// Round 1
// baseline (151.710 us; speedup 1.0000x reference)
//
#include <hip/hip_runtime.h>
#include <hip/hip_bf16.h>

// SAGAN self-attention v5. B=8, C=64, N=4096, CQ=8.
// Algebraic refactor: out = Wv.(X.P^T)/d + bv  -- V never materialized.
// prep: bf16 cast of x (Xb, same [B][C][N] layout) + Q/K projection (Q
//       pre-scaled by log2(e) so softmax uses exp2).
// attn v5 (vs v4): i-tile 32 (grid 1024 = 4 blocks/CU -> 16 waves/CU,
//       was 2 blocks/CU = 8 waves/CU grid-capped), qt=2 per wave so the
//       per-wave register set fits __launch_bounds__(256,4) (<=128 regs),
//       and P rows get stride 20 dwords (80B) so the XOR swizzle's
//       uncovered l16 bits 2-3 no longer cause 4-way bank conflicts
//       (7.4M conflict cycles/dispatch in v4).
//       Wave w owns j-slice of 1024 (32 steps x 32 j) for BOTH q-tiles
//       and ALL 64 channels:
//       p1: S^T = K.Q^T (16x16x32, K-pad, proven layout)
//       exp2 -> RTZ-pack -> wave-PRIVATE swizzled LDS (no barriers in loop)
//       p2: O' += X.P^T with X-frags double-buffered in registers
//       epilogue: tree cross-wave O' reduce, then fp32 Wv GEMM from LDS.

#define B_   8
#define C_   64
#define N_   4096
#define LOG2E 1.44269504088896340736f

typedef short bf16x8 __attribute__((ext_vector_type(8)));
typedef float f32x4  __attribute__((ext_vector_type(4)));
typedef unsigned int uint32;

#if __has_builtin(__builtin_amdgcn_exp2f)
#define EXP2(x) __builtin_amdgcn_exp2f(x)
#else
#define EXP2(x) __expf((x) * 0.69314718055994530942f)
#endif

__device__ __forceinline__ unsigned short f2bf_rn(float f) {
    union { __hip_bfloat16 h; unsigned short u; } cv;
    cv.h = __float2bfloat16(f);
    return cv.u;
}
__device__ __forceinline__ uint32 pk_rn(float lo, float hi) {
    return (uint32)f2bf_rn(lo) | ((uint32)f2bf_rn(hi) << 16);
}
// RTZ pack (1 v_perm): bias cancels in softmax ratio. Verified R2/R3.
__device__ __forceinline__ uint32 pack_rtz(float lo, float hi) {
    return __builtin_amdgcn_perm(__float_as_uint(hi), __float_as_uint(lo), 0x07060302);
}

// ---------------------------------------------------------------------------
// prep: Xb = bf16(x) (same layout), Qh/Kh = projections, [B][N][8] bf16.
// Grid: B * N/64 = 512 blocks, 256 threads.  (unchanged from v4)
// ---------------------------------------------------------------------------
__global__ __launch_bounds__(256) void prep_kernel(
    const float* __restrict__ x,
    const float* __restrict__ wq, const float* __restrict__ bq,
    const float* __restrict__ wk, const float* __restrict__ bk,
    unsigned short* __restrict__ Qh, unsigned short* __restrict__ Kh,
    unsigned short* __restrict__ Xb)
{
    __shared__ float Xs[C_][64];
    __shared__ float Wqk[16][C_];
    __shared__ float Bqk[16];

    const int t  = threadIdx.x;
    const int b  = blockIdx.x >> 6;
    const int p0 = (blockIdx.x & 63) << 6;

    for (int i = t; i < 1024; i += 256) {
        int o = i >> 6;
        Wqk[o][i & 63] = (o < 8) ? wq[i] * LOG2E : wk[i - 512];
    }
    if (t < 16) Bqk[t] = (t < 8) ? bq[t] * LOG2E : bk[t - 8];

    // stage x tile (fp32->LDS) + write bf16 cast (coalesced 4B stores)
    for (int i = t; i < 2048; i += 256) {
        int c = i >> 5, p2 = (i & 31) << 1;
        const float* xp = x + ((size_t)b * C_ + c) * N_ + p0 + p2;
        float2 v = *(const float2*)xp;
        Xs[c][p2] = v.x; Xs[c][p2 + 1] = v.y;
        *(uint32*)(Xb + ((size_t)b * C_ + c) * N_ + p0 + p2) = pk_rn(v.x, v.y);
    }
    __syncthreads();

    const int pix = t & 63, grp = t >> 6;   // grp wave-uniform
    float a[4];
    #pragma unroll
    for (int r = 0; r < 4; ++r) a[r] = Bqk[grp * 4 + r];
    for (int c = 0; c < C_; ++c) {
        float xv = Xs[c][pix];              // lanes consecutive: conflict-free
        #pragma unroll
        for (int r = 0; r < 4; ++r) a[r] += Wqk[grp * 4 + r][c] * xv;  // broadcast
    }
    #pragma unroll
    for (int r = 0; r < 4; ++r) {
        int o = grp * 4 + r;
        unsigned short hv = f2bf_rn(a[r]);
        if (o < 8) Qh[((size_t)b * N_ + p0 + pix) * 8 + o] = hv;
        else       Kh[((size_t)b * N_ + p0 + pix) * 8 + (o - 8)] = hv;
    }
}

// ---------------------------------------------------------------------------
// attn v5: grid B*N/32 = 1024 blocks (b, 32-query tile), 256 threads (4 waves).
// Wave w: j in [w*1024, w*1024+1024), both q-tiles, all 64 channels.
// __launch_bounds__(256,4): force <=128 regs -> 4 waves/SIMD (16 waves/CU).
// ---------------------------------------------------------------------------
__global__ __launch_bounds__(256, 4) void attn_mfma4_kernel(
    const unsigned short* __restrict__ Qh,
    const unsigned short* __restrict__ Kh,
    const unsigned short* __restrict__ Xb,
    const float* __restrict__ wv, const float* __restrict__ bv,
    float* __restrict__ out)
{
    // LDS map (25600 B total, 4 blocks/CU = 100 KB):
    //  loop:    [0,10240)     P: wave w at w*2560 + qt*1280 + l16*80 + swz-off
    //                         (row stride 20 dwords: l16 spread over 8 bank
    //                          bases; residual aliasing 2-way = free)
    //  epilog:  [0,16384)     stage (r1: w2->0K, w3->8K; r2: w1->0K); then Wvs
    //           [16384,24576) Or fp32 [64][32]
    //           [24576,25088) Dn fp32 [4][32]
    __shared__ __align__(16) char smem[25600];

    const int t    = threadIdx.x;
    const int w    = t >> 6;
    const int lane = t & 63;
    const int l16  = lane & 15;
    const int qd   = lane >> 4;
    const int b    = blockIdx.x >> 7;
    const int i0   = (blockIdx.x & 127) << 5;

    const bf16x8 z8 = {};
    const f32x4  zf = {};

    // Q frags (phase-1 B-operand, B[k=ch][n=q], quads 1-3 zero: K-pad)
    bf16x8 qf[2];
    #pragma unroll
    for (int qt = 0; qt < 2; ++qt) {
        qf[qt] = z8;
        if (qd == 0)
            qf[qt] = *(const bf16x8*)(Qh + ((size_t)b * N_ + i0 + qt * 16 + l16) * 8);
    }

    const unsigned short* Kp = Kh + ((size_t)b * N_ + w * 1024) * 8;
    const unsigned short* Xp = Xb + (size_t)b * C_ * N_ + w * 1024;

    f32x4 acc[4][2];   // [ct][qt]: O'(c=ct*16+qd*4+r, q=qt*16+l16)
    #pragma unroll
    for (int ct = 0; ct < 4; ++ct)
        #pragma unroll
        for (int qt = 0; qt < 2; ++qt) acc[ct][qt] = zf;
    float dsum[2] = {0.f, 0.f};

    // wave-private P addressing: stride-20-dword rows + XOR swizzle
    const int swz   = (l16 & 3) << 2;
    const int wbase = w * 2560 + l16 * 80;
    int woff[2];
    #pragma unroll
    for (int jt = 0; jt < 2; ++jt) woff[jt] = ((jt * 8 + qd * 2) ^ swz) << 2;
    const int roff = ((qd * 4) ^ swz) << 2;

    // preload step 0
    bf16x8 kf[2][2], xf[2][4];
    #pragma unroll
    for (int jt = 0; jt < 2; ++jt) {
        kf[0][jt] = z8;
        if (qd == 0) kf[0][jt] = *(const bf16x8*)(Kp + (jt * 16 + l16) * 8);
    }
    #pragma unroll
    for (int ct = 0; ct < 4; ++ct)
        xf[0][ct] = *(const bf16x8*)(Xp + (size_t)(ct * 16 + l16) * N_ + qd * 8);

    #pragma unroll 2
    for (int s = 0; s < 32; ++s) {
        const int cur = s & 1, nxt = cur ^ 1;
        const int jb = s * 32;

        // phase 1: S^T[j][q] (rows j=jt*16+qd*4+r, col q=l16)
        f32x4 sf[2][2];
        #pragma unroll
        for (int jt = 0; jt < 2; ++jt)
            #pragma unroll
            for (int qt = 0; qt < 2; ++qt)
                sf[jt][qt] = __builtin_amdgcn_mfma_f32_16x16x32_bf16(kf[cur][jt], qf[qt], zf, 0, 0, 0);

        // prefetch next step's K and X frags (latency hidden behind exp/p2)
        if (s < 31) {
            #pragma unroll
            for (int jt = 0; jt < 2; ++jt) {
                bf16x8 nk = z8;
                if (qd == 0) nk = *(const bf16x8*)(Kp + (size_t)(jb + 32 + jt * 16 + l16) * 8);
                kf[nxt][jt] = nk;
            }
            #pragma unroll
            for (int ct = 0; ct < 4; ++ct)
                xf[nxt][ct] = *(const bf16x8*)(Xp + (size_t)(ct * 16 + l16) * N_ + jb + 32 + qd * 8);
        }

        // exp2 -> denom + pack to wave-private LDS
        #pragma unroll
        for (int jt = 0; jt < 2; ++jt)
            #pragma unroll
            for (int qt = 0; qt < 2; ++qt) {
                float e0 = EXP2(sf[jt][qt][0]);
                float e1 = EXP2(sf[jt][qt][1]);
                float e2 = EXP2(sf[jt][qt][2]);
                float e3 = EXP2(sf[jt][qt][3]);
                dsum[qt] += (e0 + e1) + (e2 + e3);
                uint2 u;
                u.x = pack_rtz(e0, e1);
                u.y = pack_rtz(e2, e3);
                *(uint2*)(smem + wbase + qt * 1280 + woff[jt]) = u;
            }

        // phase 2: O' += X . P^T  (A=X[m=c][k=j], B=P^T[k=j][n=q])
        #pragma unroll
        for (int qt = 0; qt < 2; ++qt) {
            bf16x8 pb = *(const bf16x8*)(smem + wbase + qt * 1280 + roff);
            #pragma unroll
            for (int ct = 0; ct < 4; ++ct)
                acc[ct][qt] = __builtin_amdgcn_mfma_f32_16x16x32_bf16(xf[cur][ct], pb, acc[ct][qt], 0, 0, 0);
        }
    }

    // ---- denominator partials -> Dn[w][32] ----
    #pragma unroll
    for (int qt = 0; qt < 2; ++qt) {
        float v = dsum[qt];
        v += __shfl_xor(v, 16, 64);
        v += __shfl_xor(v, 32, 64);
        if (qd == 0) *(float*)(smem + 24576 + (w * 32 + qt * 16 + l16) * 4) = v;
    }

    // ---- cross-wave O' tree reduce (P region dead after S1) ----
    __syncthreads();                                   // S1
    if (w >= 2) {
        char* rb = smem + (w - 2) * 8192;
        #pragma unroll
        for (int ct = 0; ct < 4; ++ct)
            #pragma unroll
            for (int qt = 0; qt < 2; ++qt)
                *(f32x4*)(rb + (ct * 2 + qt) * 1024 + lane * 16) = acc[ct][qt];
    }
    __syncthreads();                                   // S2
    if (w < 2) {
        const char* rb = smem + w * 8192;
        #pragma unroll
        for (int ct = 0; ct < 4; ++ct)
            #pragma unroll
            for (int qt = 0; qt < 2; ++qt)
                acc[ct][qt] += *(const f32x4*)(rb + (ct * 2 + qt) * 1024 + lane * 16);
    }
    __syncthreads();                                   // S3
    if (w == 1) {
        char* rb = smem;
        #pragma unroll
        for (int ct = 0; ct < 4; ++ct)
            #pragma unroll
            for (int qt = 0; qt < 2; ++qt)
                *(f32x4*)(rb + (ct * 2 + qt) * 1024 + lane * 16) = acc[ct][qt];
    }
    __syncthreads();                                   // S4
    if (w == 0) {
        #pragma unroll
        for (int ct = 0; ct < 4; ++ct)
            #pragma unroll
            for (int qt = 0; qt < 2; ++qt)
                acc[ct][qt] += *(const f32x4*)(smem + (ct * 2 + qt) * 1024 + lane * 16);
        float* Or = (float*)(smem + 16384);
        #pragma unroll
        for (int ct = 0; ct < 4; ++ct)
            #pragma unroll
            for (int qt = 0; qt < 2; ++qt)
                #pragma unroll
                for (int r = 0; r < 4; ++r)
                    Or[(ct * 16 + qd * 4 + r) * 32 + qt * 16 + l16] = acc[ct][qt][r];
    }
    __syncthreads();                                   // S5
    {   // stage Wv fp32 into [0,16K) (stage region fully consumed)
        float* Wvs = (float*)smem;
        for (int i = t; i < 4096; i += 256) Wvs[i] = wv[i];
    }
    __syncthreads();                                   // S6

    // ---- epilogue: out = Wv.O'/d + bv, fp32 ----
    const int q = t & 31, grp = t >> 5;
    const float* Wvs = (const float*)smem;
    const float* Or  = (const float*)(smem + 16384);
    const float* Dn  = (const float*)(smem + 24576);
    const float inv = 1.0f / (Dn[q] + Dn[32 + q] + Dn[64 + q] + Dn[96 + q]);
    float o[8];
    #pragma unroll
    for (int r = 0; r < 8; ++r) o[r] = 0.f;
    for (int k = 0; k < 64; ++k) {
        float ov = Or[k * 32 + q];                      // lanes consecutive q
        #pragma unroll
        for (int r = 0; r < 8; ++r)
            o[r] += Wvs[(grp * 8 + r) * 64 + k] * ov;   // broadcast
    }
    #pragma unroll
    for (int r = 0; r < 8; ++r)
        out[((size_t)b * C_ + grp * 8 + r) * N_ + i0 + q] = o[r] * inv + bv[grp * 8 + r];
}

// ---------------------------------------------------------------------------
// Fallback (workspace too small): round-1 fused fp32 flash kernel (verified).
// ---------------------------------------------------------------------------
__global__ __launch_bounds__(256) void attn_fused_fallback(
    const float* __restrict__ x,
    const float* __restrict__ wq, const float* __restrict__ bq,
    const float* __restrict__ wk, const float* __restrict__ bk,
    const float* __restrict__ wv, const float* __restrict__ bv,
    float* __restrict__ out)
{
    __shared__ float Qs[64][8];
    __shared__ float Ks[8][64];
    __shared__ float Vs[64][C_];
    __shared__ float Ws[64][64 + 1];
    __shared__ float Xs[C_ * 64];
    __shared__ float Wks[8][C_];
    __shared__ float Wvs[C_][C_ + 1];

    const int t     = threadIdx.x;
    const int b     = blockIdx.x / (N_ / 64);
    const int i0    = (blockIdx.x % (N_ / 64)) * 64;
    const int jlane = t & 63;
    const int wgrp  = t >> 6;

    for (int l = t; l < 8 * C_;  l += 256) Wks[l >> 6][l & 63] = wk[l];
    for (int l = t; l < C_ * C_; l += 256) Wvs[l >> 6][l & 63] = wv[l];
    for (int l = t; l < C_ * 64; l += 256)
        Xs[(l >> 6) * 64 + (l & 63)] = x[((size_t)b * C_ + (l >> 6)) * N_ + i0 + (l & 63)];
    __syncthreads();
    {
        int qi = jlane;
        #pragma unroll
        for (int r = 0; r < 2; ++r) {
            int cc = wgrp * 2 + r;
            float a = bq[cc];
            for (int c = 0; c < C_; ++c) a += wq[cc * C_ + c] * Xs[c * 64 + qi];
            Qs[qi][cc] = a;
        }
    }
    __syncthreads();

    const int qi2 = t >> 2;
    const int cb  = (t & 3) << 4;
    float accv[16];
    #pragma unroll
    for (int r = 0; r < 16; ++r) accv[r] = 0.f;
    float denom = 0.f;

    for (int j0 = 0; j0 < N_; j0 += 64) {
        for (int l = t; l < C_ * 64; l += 256)
            Xs[(l >> 6) * 64 + (l & 63)] = x[((size_t)b * C_ + (l >> 6)) * N_ + j0 + (l & 63)];
        __syncthreads();
        {
            int j = jlane;
            #pragma unroll
            for (int r = 0; r < 2; ++r) {
                int cc = wgrp * 2 + r;
                float a = bk[cc];
                for (int c = 0; c < C_; ++c) a += Wks[cc][c] * Xs[c * 64 + j];
                Ks[cc][j] = a;
            }
        }
        {
            int vc = jlane;
            #pragma unroll 2
            for (int r = 0; r < 16; ++r) {
                int j = wgrp * 16 + r;
                float a = bv[vc];
                for (int c = 0; c < C_; ++c) a += Wvs[vc][c] * Xs[c * 64 + j];
                Vs[j][vc] = a;
            }
        }
        __syncthreads();
        {
            float kreg[8];
            #pragma unroll
            for (int cc = 0; cc < 8; ++cc) kreg[cc] = Ks[cc][jlane];
            #pragma unroll 4
            for (int r = 0; r < 16; ++r) {
                int qi = wgrp * 16 + r;
                float e = 0.f;
                #pragma unroll
                for (int cc = 0; cc < 8; ++cc) e += Qs[qi][cc] * kreg[cc];
                Ws[qi][jlane] = __expf(e);
            }
        }
        __syncthreads();
        #pragma unroll 4
        for (int j = 0; j < 64; ++j) {
            float wv2 = Ws[qi2][j];
            denom += wv2;
            const float4* vrow = (const float4*)(&Vs[j][cb]);
            float4 v0 = vrow[0], v1 = vrow[1], v2 = vrow[2], v3 = vrow[3];
            accv[0]  += wv2 * v0.x; accv[1]  += wv2 * v0.y; accv[2]  += wv2 * v0.z; accv[3]  += wv2 * v0.w;
            accv[4]  += wv2 * v1.x; accv[5]  += wv2 * v1.y; accv[6]  += wv2 * v1.z; accv[7]  += wv2 * v1.w;
            accv[8]  += wv2 * v2.x; accv[9]  += wv2 * v2.y; accv[10] += wv2 * v2.z; accv[11] += wv2 * v2.w;
            accv[12] += wv2 * v3.x; accv[13] += wv2 * v3.y; accv[14] += wv2 * v3.z; accv[15] += wv2 * v3.w;
        }
        __syncthreads();
    }

    const float inv = 1.0f / denom;
    #pragma unroll
    for (int r = 0; r < 16; ++r)
        out[((size_t)b * C_ + cb + r) * N_ + i0 + qi2] = accv[r] * inv;
}

// ---------------------------------------------------------------------------
extern "C" void kernel_launch(void* const* d_in, const int* in_sizes, int n_in,
                              void* d_out, int out_size, void* d_ws, size_t ws_size,
                              hipStream_t stream)
{
    const float* x  = (const float*)d_in[0];
    const float* wq = (const float*)d_in[1];
    const float* bq = (const float*)d_in[2];
    const float* wk = (const float*)d_in[3];
    const float* bk = (const float*)d_in[4];
    const float* wv = (const float*)d_in[5];
    const float* bv = (const float*)d_in[6];
    float* out = (float*)d_out;

    const size_t nQ = (size_t)B_ * N_ * 8;        // 256K elems
    const size_t nX = (size_t)B_ * C_ * N_;       // 2M elems
    const size_t needed = (2 * nQ + nX) * sizeof(unsigned short);   // 5 MB

    if (ws_size >= needed) {
        unsigned short* Qh = (unsigned short*)d_ws;
        unsigned short* Kh = Qh + nQ;
        unsigned short* Xb = Kh + nQ;
        prep_kernel<<<B_ * (N_ / 64), 256, 0, stream>>>(x, wq, bq, wk, bk, Qh, Kh, Xb);
        attn_mfma4_kernel<<<B_ * (N_ / 32), 256, 0, stream>>>(Qh, Kh, Xb, wv, bv, out);
    } else {
        attn_fused_fallback<<<B_ * (N_ / 64), 256, 0, stream>>>(x, wq, bq, wk, bk, wv, bv, out);
    }
}